// Round 2
// baseline (13765.347 us; speedup 1.0000x reference)
//
#include <hip/hip_runtime.h>
#include <hip/hip_bf16.h>

#define B_ 4
#define H_ 16
#define S_ 2048
#define D_ 128

typedef unsigned short u16;
typedef unsigned int u32;

__device__ __forceinline__ float bf2f(u16 x) {
    return __uint_as_float(((u32)x) << 16);
}

__device__ __forceinline__ u16 f2bf(float f) {
    u32 u = __float_as_uint(f);
    u32 lsb = (u >> 16) & 1u;
    u += 0x7fffu + lsb;           // round-to-nearest-even
    return (u16)(u >> 16);
}

// ---------------------------------------------------------------------------
// Dtype detector: reads first 4096 u32 words of Q; low 16 bits as bf16.
// True-bf16 data: those are N(0,1) samples, |x| <= ~6.  fp32 data: they are
// low mantissa bits -> uniform-ish exponent -> ~47% have |x| > 64 (or inf/nan).
// flag = 1 -> inputs are fp32;  flag = 0 -> inputs are bf16.
// ---------------------------------------------------------------------------
__global__ void detect_dtype_kernel(const u32* __restrict__ q, int* __restrict__ flag) {
    __shared__ int cnt;
    if (threadIdx.x == 0) cnt = 0;
    __syncthreads();
    int c = 0;
    for (int i = threadIdx.x; i < 4096; i += 256) {
        float lo = bf2f((u16)(q[i] & 0xffffu));
        if (!(fabsf(lo) <= 64.0f)) c++;   // catches >64, inf, NaN
    }
    atomicAdd(&cnt, c);
    __syncthreads();
    if (threadIdx.x == 0) *flag = (cnt > 256) ? 1 : 0;
}

// ---------------------------------------------------------------------------
// bf16 path (runs only if *flag == 0). One block per (b,h,q) row.
// ---------------------------------------------------------------------------
__global__ __launch_bounds__(256) void attn_bf16_kernel(
    const u16* __restrict__ Q, const u16* __restrict__ K, const u16* __restrict__ V,
    u16* __restrict__ Out, u16* __restrict__ W, const int* __restrict__ flag)
{
    if (*flag != 0) return;

    __shared__ float qs[D_];
    __shared__ float sc[S_];
    __shared__ float red[8];
    __shared__ float ot[512];

    const int tid = threadIdx.x;
    const int idx = blockIdx.x;
    const int q   = idx & (S_ - 1);
    const int bh  = idx >> 11;
    const size_t rowQ = (size_t)idx * D_;
    const u16* Kb = K + (size_t)bh * S_ * D_;
    const u16* Vb = V + (size_t)bh * S_ * D_;
    const int nk = q + 1;
    const float scale = 0.08838834764831845f;

    if (tid < D_) qs[tid] = bf2f(Q[rowQ + tid]) * scale;
    __syncthreads();

    float lmax = -1e30f;
    for (int k = tid; k < nk; k += 256) {
        const uint4* K4 = reinterpret_cast<const uint4*>(Kb + (size_t)k * D_);
        float acc = 0.f;
        #pragma unroll
        for (int c = 0; c < D_ / 8; ++c) {
            uint4 u = K4[c];
            const int d = c * 8;
            acc += qs[d + 0] * bf2f((u16)(u.x & 0xffffu));
            acc += qs[d + 1] * bf2f((u16)(u.x >> 16));
            acc += qs[d + 2] * bf2f((u16)(u.y & 0xffffu));
            acc += qs[d + 3] * bf2f((u16)(u.y >> 16));
            acc += qs[d + 4] * bf2f((u16)(u.z & 0xffffu));
            acc += qs[d + 5] * bf2f((u16)(u.z >> 16));
            acc += qs[d + 6] * bf2f((u16)(u.w & 0xffffu));
            acc += qs[d + 7] * bf2f((u16)(u.w >> 16));
        }
        sc[k] = acc;
        lmax = fmaxf(lmax, acc);
    }

    #pragma unroll
    for (int off = 32; off > 0; off >>= 1)
        lmax = fmaxf(lmax, __shfl_down(lmax, off, 64));
    if ((tid & 63) == 0) red[tid >> 6] = lmax;
    __syncthreads();
    const float mx = fmaxf(fmaxf(red[0], red[1]), fmaxf(red[2], red[3]));

    float lsum = 0.f;
    for (int k = tid; k < nk; k += 256) {
        float e = __expf(sc[k] - mx);
        sc[k] = e;
        lsum += e;
    }
    #pragma unroll
    for (int off = 32; off > 0; off >>= 1)
        lsum += __shfl_down(lsum, off, 64);
    if ((tid & 63) == 0) red[4 + (tid >> 6)] = lsum;
    __syncthreads();
    const float rsum = 1.0f / (red[4] + red[5] + red[6] + red[7]);

    u32* Wrow2 = reinterpret_cast<u32*>(W + (size_t)idx * S_);
    for (int k2 = tid; k2 < S_ / 2; k2 += 256) {
        const int k0 = 2 * k2, k1 = 2 * k2 + 1;
        float w0 = (k0 < nk) ? sc[k0] * rsum : 0.f;
        float w1 = (k1 < nk) ? sc[k1] * rsum : 0.f;
        if (k0 < nk) sc[k0] = w0;
        if (k1 < nk) sc[k1] = w1;
        Wrow2[k2] = (u32)f2bf(w0) | ((u32)f2bf(w1) << 16);
    }
    __syncthreads();

    const int d2   = tid & 63;
    const int part = tid >> 6;
    const u32* V2 = reinterpret_cast<const u32*>(Vb);
    float a0 = 0.f, a1 = 0.f;
    for (int k = part; k < nk; k += 4) {
        const u32 u = V2[(size_t)k * (D_ / 2) + d2];
        const float w = sc[k];
        a0 += w * bf2f((u16)(u & 0xffffu));
        a1 += w * bf2f((u16)(u >> 16));
    }
    ot[part * D_ + 2 * d2]     = a0;
    ot[part * D_ + 2 * d2 + 1] = a1;
    __syncthreads();

    if (tid < D_) {
        const float o = ot[tid] + ot[D_ + tid] + ot[2 * D_ + tid] + ot[3 * D_ + tid];
        Out[rowQ + tid] = f2bf(o);
    }
}

// ---------------------------------------------------------------------------
// fp32 path (runs only if *flag == 1). Identical structure, float I/O.
// ---------------------------------------------------------------------------
__global__ __launch_bounds__(256) void attn_f32_kernel(
    const float* __restrict__ Q, const float* __restrict__ K, const float* __restrict__ V,
    float* __restrict__ Out, float* __restrict__ W, const int* __restrict__ flag)
{
    if (*flag != 1) return;

    __shared__ float qs[D_];
    __shared__ float sc[S_];
    __shared__ float red[8];
    __shared__ float ot[512];

    const int tid = threadIdx.x;
    const int idx = blockIdx.x;
    const int q   = idx & (S_ - 1);
    const int bh  = idx >> 11;
    const size_t rowQ = (size_t)idx * D_;
    const float* Kb = K + (size_t)bh * S_ * D_;
    const float* Vb = V + (size_t)bh * S_ * D_;
    const int nk = q + 1;
    const float scale = 0.08838834764831845f;

    if (tid < D_) qs[tid] = Q[rowQ + tid] * scale;
    __syncthreads();

    float lmax = -1e30f;
    for (int k = tid; k < nk; k += 256) {
        const float4* K4 = reinterpret_cast<const float4*>(Kb + (size_t)k * D_);
        float acc = 0.f;
        #pragma unroll
        for (int c = 0; c < D_ / 4; ++c) {
            float4 u = K4[c];
            const int d = c * 4;
            acc += qs[d + 0] * u.x;
            acc += qs[d + 1] * u.y;
            acc += qs[d + 2] * u.z;
            acc += qs[d + 3] * u.w;
        }
        sc[k] = acc;
        lmax = fmaxf(lmax, acc);
    }

    #pragma unroll
    for (int off = 32; off > 0; off >>= 1)
        lmax = fmaxf(lmax, __shfl_down(lmax, off, 64));
    if ((tid & 63) == 0) red[tid >> 6] = lmax;
    __syncthreads();
    const float mx = fmaxf(fmaxf(red[0], red[1]), fmaxf(red[2], red[3]));

    float lsum = 0.f;
    for (int k = tid; k < nk; k += 256) {
        float e = __expf(sc[k] - mx);
        sc[k] = e;
        lsum += e;
    }
    #pragma unroll
    for (int off = 32; off > 0; off >>= 1)
        lsum += __shfl_down(lsum, off, 64);
    if ((tid & 63) == 0) red[4 + (tid >> 6)] = lsum;
    __syncthreads();
    const float rsum = 1.0f / (red[4] + red[5] + red[6] + red[7]);

    float2* Wrow2 = reinterpret_cast<float2*>(W + (size_t)idx * S_);
    for (int k2 = tid; k2 < S_ / 2; k2 += 256) {
        const int k0 = 2 * k2, k1 = 2 * k2 + 1;
        float w0 = (k0 < nk) ? sc[k0] * rsum : 0.f;
        float w1 = (k1 < nk) ? sc[k1] * rsum : 0.f;
        if (k0 < nk) sc[k0] = w0;
        if (k1 < nk) sc[k1] = w1;
        Wrow2[k2] = make_float2(w0, w1);
    }
    __syncthreads();

    const int d2   = tid & 63;
    const int part = tid >> 6;
    const float2* V2 = reinterpret_cast<const float2*>(Vb);
    float a0 = 0.f, a1 = 0.f;
    for (int k = part; k < nk; k += 4) {
        const float2 u = V2[(size_t)k * (D_ / 2) + d2];
        const float w = sc[k];
        a0 += w * u.x;
        a1 += w * u.y;
    }
    ot[part * D_ + 2 * d2]     = a0;
    ot[part * D_ + 2 * d2 + 1] = a1;
    __syncthreads();

    if (tid < D_) {
        const float o = ot[tid] + ot[D_ + tid] + ot[2 * D_ + tid] + ot[3 * D_ + tid];
        Out[rowQ + tid] = o;
    }
}

extern "C" void kernel_launch(void* const* d_in, const int* in_sizes, int n_in,
                              void* d_out, int out_size, void* d_ws, size_t ws_size,
                              hipStream_t stream) {
    int* flag = (int*)d_ws;

    detect_dtype_kernel<<<dim3(1), dim3(256), 0, stream>>>((const u32*)d_in[0], flag);

    // bf16 interpretation
    {
        const u16* Q = (const u16*)d_in[0];
        const u16* K = (const u16*)d_in[1];
        const u16* V = (const u16*)d_in[2];
        u16* Out = (u16*)d_out;
        u16* W   = Out + (size_t)B_ * H_ * S_ * D_;
        attn_bf16_kernel<<<dim3(B_ * H_ * S_), dim3(256), 0, stream>>>(Q, K, V, Out, W, flag);
    }

    // fp32 interpretation
    {
        const float* Q = (const float*)d_in[0];
        const float* K = (const float*)d_in[1];
        const float* V = (const float*)d_in[2];
        float* Out = (float*)d_out;
        float* W   = Out + (size_t)B_ * H_ * S_ * D_;
        attn_f32_kernel<<<dim3(B_ * H_ * S_), dim3(256), 0, stream>>>(Q, K, V, Out, W, flag);
    }
}